// Round 9
// baseline (71.398 us; speedup 1.0000x reference)
//
#include <hip/hip_runtime.h>
#include <math.h>

// Triangle-triangle intersection, bit-exact vs the numpy/JAX reference.
//  - Final decisions always come from the reference pipeline: ref op order,
//    EPS snap at 1e-6, fp contract OFF, IEEE divides.
//  - Structure: triu 32x32 tiles + survivor compaction (best measured R5-R8).
//  - R9: (1) phase-1 gate uses fmaf-chain distances + a conservative margin
//    (safe over-accept; phase 2 now applies the EXACT ssv/ssu test too);
//    (2) phase-2 computes only the 2 valid edges' t values (2 IEEE divides,
//    bitwise-identical to ref) with a rare-path fallback for snapped zeros.

static constexpr float EPS_SNAP = 1e-6f;
static constexpr int TS = 32;  // tile size; n=2048 divisible

__device__ __forceinline__ float snapz(float x) {
    return (fabsf(x) < EPS_SNAP) ? 0.0f : x;
}

// Reference 3-edge interval (rare path + exactness anchor).
__device__ __forceinline__ void tri_interval(const float p[3], const float d[3],
                                             float& tmin, float& tmax) {
#pragma clang fp contract(off)
    tmin = INFINITY;
    tmax = -INFINITY;
#pragma unroll
    for (int e = 0; e < 3; ++e) {
        const int i0 = e;
        const int i1 = (e + 1) % 3;  // edges (0,1),(1,2),(2,0)
        const float di = d[i0], dj = d[i1];
        const float pi = p[i0], pj = p[i1];
        const bool valid = (di * dj <= 0.0f) && !((di == 0.0f) && (dj == 0.0f));
        const float denom = di - dj;
        const float dsafe = (denom == 0.0f) ? 1.0f : denom;
        const float t = pi + ((pj - pi) * di) / dsafe;
        if (valid) {
            tmin = fminf(tmin, t);
            tmax = fmaxf(tmax, t);
        }
    }
}

// Fast 2-edge interval: valid when all d are snapped-nonzero and mixed-sign.
// The two valid edges are those incident to the odd-signed vertex o; both are
// computed with the reference's (i,j) orientation and formula -> bitwise
// identical t values. (If signs are NOT mixed -- margin-gate leaks -- the
// result is garbage but gets masked by the exact ss test afterwards.)
__device__ __forceinline__ void tri_interval2(const float p[3], const float d[3],
                                              float& tmin, float& tmax) {
#pragma clang fp contract(off)
    const bool s0 = d[0] > 0.0f, s1 = d[1] > 0.0f, s2 = d[2] > 0.0f;
    const int o = (s0 == s1) ? 2 : ((s1 == s2) ? 0 : 1);
    const float po = (o == 0) ? p[0] : ((o == 1) ? p[1] : p[2]);
    const float dO = (o == 0) ? d[0] : ((o == 1) ? d[1] : d[2]);
    const float pj = (o == 0) ? p[1] : ((o == 1) ? p[2] : p[0]);  // (o+1)%3
    const float dj = (o == 0) ? d[1] : ((o == 1) ? d[2] : d[0]);
    const float pi = (o == 0) ? p[2] : ((o == 1) ? p[0] : p[1]);  // (o+2)%3
    const float di = (o == 0) ? d[2] : ((o == 1) ? d[0] : d[1]);
    const float tA = po + ((pj - po) * dO) / (dO - dj);  // ref edge (o, o+1)
    const float tB = pi + ((po - pi) * di) / (di - dO);  // ref edge (o+2, o)
    tmin = fminf(tA, tB);
    tmax = fmaxf(tA, tB);
}

__global__ __launch_bounds__(256, 6) void tile_kernel(
    const float* __restrict__ tri, float* __restrict__ out, int n)
{
#pragma clang fp contract(off)
    const int nt = n / TS;  // 64
    int k = blockIdx.x, tr = 0;
    while (k >= nt - tr) { k -= nt - tr; ++tr; }
    const int tc = tr + k;
    const int R = tr * TS, C = tc * TS;

    __shared__ float Asf[TS * 12];            // row tris, padded to 12 floats
    __shared__ float Bsf[TS * 12];            // col tris
    __shared__ float4 Apl[TS], Bpl[TS];       // planes (normal, offset)
    __shared__ float Sres[TS][TS + 1];        // result tile
    __shared__ unsigned short qbuf[TS * TS];  // survivor queue (r<<5|c)
    __shared__ float tstat[4];                // mA, mB, nA, nB (tile maxes)
    __shared__ int s_cnt;

    const int tx = threadIdx.x;  // 0..31 column in tile
    const int ty = threadIdx.y;  // 0..7
    const int t = ty * TS + tx;  // 0..255
    const int lane = t & 63;

    // ---- stage verts (coalesced dwords -> padded LDS rows) ----
    if (t == 0) s_cnt = 0;
    for (int g = t; g < TS * 9; g += 256) {
        const int a = g / 9, c9 = g - a * 9;
        Asf[a * 12 + c9] = tri[(size_t)R * 9 + g];
        Bsf[a * 12 + c9] = tri[(size_t)C * 9 + g];
    }
    // ---- planes from global, concurrent with staging (threads 0..63) ----
    if (t < 2 * TS) {
        const int idx = (t < TS) ? (R + t) : (C + (t - TS));
        const float* V = tri + (size_t)idx * 9;
        float Vv[9];
#pragma unroll
        for (int q = 0; q < 9; ++q) Vv[q] = V[q];
        const float e1x = Vv[3] - Vv[0], e1y = Vv[4] - Vv[1], e1z = Vv[5] - Vv[2];
        const float e2x = Vv[6] - Vv[0], e2y = Vv[7] - Vv[1], e2z = Vv[8] - Vv[2];
        const float nx = e1y * e2z - e1z * e2y;
        const float ny = e1z * e2x - e1x * e2z;
        const float nz = e1x * e2y - e1y * e2x;
        const float d = -(((nx * Vv[0]) + (ny * Vv[1])) + (nz * Vv[2]));
        if (t < TS) Apl[t] = make_float4(nx, ny, nz, d);
        else        Bpl[t - TS] = make_float4(nx, ny, nz, d);
    }
    __syncthreads();

    // ---- tile max reduction (one wave per stat, shfl butterfly) ----
    {
        const int w = t >> 6;  // 0..3
        float lm = 0.0f;
        if (w < 2) {
            const float* S = (w == 0) ? Asf : Bsf;
            const int row = lane & 31, half = lane >> 5;
            const int base = row * 12 + half * 5;
            const int cnt = half ? 4 : 5;  // floats 0..4 / 5..8 (skip padding)
            for (int q = 0; q < cnt; ++q) lm = fmaxf(lm, fabsf(S[base + q]));
        } else if (lane < TS) {
            const float4 p = (w == 2) ? Apl[lane] : Bpl[lane];
            lm = fmaxf(fmaxf(fabsf(p.x), fabsf(p.y)), fabsf(p.z));
        }
#pragma unroll
        for (int off = 32; off > 0; off >>= 1) lm = fmaxf(lm, __shfl_xor(lm, off));
        if (lane == 0) tstat[w] = lm;
    }
    __syncthreads();

    // Conservative gate thresholds: >=4.8x the provable |d_fma - d_ref| bound.
    const float sumM = tstat[0] + tstat[1];
    const float thrV = EPS_SNAP + 6e-6f * (tstat[3] * sumM);  // A verts vs B plane
    const float thrU = EPS_SNAP + 6e-6f * (tstat[2] * sumM);  // B verts vs A plane

    // ---- phase 1: margin-gated straddle test (fmaf dots), compact survivors --
    float Bv[9];
    {
        const float4 b0 = *(const float4*)&Bsf[tx * 12];
        const float4 b1 = *(const float4*)&Bsf[tx * 12 + 4];
        Bv[0] = b0.x; Bv[1] = b0.y; Bv[2] = b0.z; Bv[3] = b0.w;
        Bv[4] = b1.x; Bv[5] = b1.y; Bv[6] = b1.z; Bv[7] = b1.w;
        Bv[8] = Bsf[tx * 12 + 8];
    }
    const float4 pb = Bpl[tx];

    for (int kk = 0; kk < 4; ++kk) {
        const int r = ty + 8 * kk;
        const float4 a0 = *(const float4*)&Asf[r * 12];
        const float4 a1 = *(const float4*)&Asf[r * 12 + 4];
        const float a8 = Asf[r * 12 + 8];
        const float4 pa = Apl[r];
        // fmaf-chain distances (NOT ref order -- margin covers the difference)
        const float dv0 = fmaf(a0.x, pb.x, fmaf(a0.y, pb.y, fmaf(a0.z, pb.z, pb.w)));
        const float dv1 = fmaf(a0.w, pb.x, fmaf(a1.x, pb.y, fmaf(a1.y, pb.z, pb.w)));
        const float dv2 = fmaf(a1.z, pb.x, fmaf(a1.w, pb.y, fmaf(a8, pb.z, pb.w)));
        const float du0 = fmaf(Bv[0], pa.x, fmaf(Bv[1], pa.y, fmaf(Bv[2], pa.z, pa.w)));
        const float du1 = fmaf(Bv[3], pa.x, fmaf(Bv[4], pa.y, fmaf(Bv[5], pa.z, pa.w)));
        const float du2 = fmaf(Bv[6], pa.x, fmaf(Bv[7], pa.y, fmaf(Bv[8], pa.z, pa.w)));
        const float mnv = fminf(fminf(dv0, dv1), dv2), mxv = fmaxf(fmaxf(dv0, dv1), dv2);
        const float mnu = fminf(fminf(du0, du1), du2), mxu = fmaxf(fmaxf(du0, du1), du2);
        const bool rejv = (mnv >= thrV) || (mxv <= -thrV);  // ref surely rejects
        const bool reju = (mnu >= thrU) || (mxu <= -thrU);
        const int i = R + r, j = C + tx;
        const bool surv = !rejv && !reju && (i != j);
        Sres[r][tx] = (i == j) ? 1.0f : 0.0f;  // survivors overwritten in phase 2
        const unsigned long long m = __ballot(surv);
        int wb = 0;
        if (lane == 0) {
            const int wcnt = __popcll(m);
            if (wcnt) wb = atomicAdd(&s_cnt, wcnt);
        }
        wb = __shfl(wb, 0);
        if (surv) {
            const int pos = wb + __popcll(m & ((1ull << lane) - 1ull));
            qbuf[pos] = (unsigned short)((r << 5) | tx);
        }
    }
    __syncthreads();

    // ---- phase 2: exact reference pipeline on survivors ----
    const int total = s_cnt;
    for (int q = t; q < total; q += 256) {
        const int e = qbuf[q];
        const int r = e >> 5, c = e & 31;

        const float4 pa = Apl[r];
        const float4 pq = Bpl[c];
        const float nax = pa.x, nay = pa.y, naz = pa.z, da = pa.w;
        const float nbx = pq.x, nby = pq.y, nbz = pq.z, db = pq.w;

        // exact snapped distances (reference order)
        float dv[3], du[3];
        {
            const float4 a0 = *(const float4*)&Asf[r * 12];
            const float4 a1 = *(const float4*)&Asf[r * 12 + 4];
            const float a8 = Asf[r * 12 + 8];
            dv[0] = snapz((((a0.x * nbx) + (a0.y * nby)) + (a0.z * nbz)) + db);
            dv[1] = snapz((((a0.w * nbx) + (a1.x * nby)) + (a1.y * nbz)) + db);
            dv[2] = snapz((((a1.z * nbx) + (a1.w * nby)) + (a8 * nbz)) + db);
            const float4 b0 = *(const float4*)&Bsf[c * 12];
            const float4 b1 = *(const float4*)&Bsf[c * 12 + 4];
            const float b8 = Bsf[c * 12 + 8];
            du[0] = snapz((((b0.x * nax) + (b0.y * nay)) + (b0.z * naz)) + da);
            du[1] = snapz((((b0.w * nax) + (b1.x * nay)) + (b1.y * naz)) + da);
            du[2] = snapz((((b1.z * nax) + (b1.w * nay)) + (b8 * naz)) + da);
        }

        // exact one-sided tests (margin gate may leak ss pairs)
        const bool ssv = (dv[0] > 0.0f && dv[1] > 0.0f && dv[2] > 0.0f) ||
                         (dv[0] < 0.0f && dv[1] < 0.0f && dv[2] < 0.0f);
        const bool ssu = (du[0] > 0.0f && du[1] > 0.0f && du[2] > 0.0f) ||
                         (du[0] < 0.0f && du[1] < 0.0f && du[2] < 0.0f);

        // plane-plane line direction, dominant axis (first-occurrence argmax)
        const float Dx = nay * nbz - naz * nby;
        const float Dy = naz * nbx - nax * nbz;
        const float Dz = nax * nby - nay * nbx;
        const float m0 = fabsf(Dx), m1 = fabsf(Dy), m2 = fabsf(Dz);
        int axm = 0;
        float mm = m0;
        if (m1 > mm) { axm = 1; mm = m1; }
        if (m2 > mm) { axm = 2; }

        float pv[3], pu[3];
#pragma unroll
        for (int v = 0; v < 3; ++v) {
            pv[v] = Asf[r * 12 + 3 * v + axm];
            pu[v] = Bsf[c * 12 + 3 * v + axm];
        }

        // 2-divide fast path; rare snapped-zero lanes redo the exact 3-edge ref
        float t0v, t1v, t0u, t1u;
        tri_interval2(pv, dv, t0v, t1v);
        tri_interval2(pu, du, t0u, t1u);
        const bool hzA = (dv[0] == 0.0f) || (dv[1] == 0.0f) || (dv[2] == 0.0f);
        const bool hzB = (du[0] == 0.0f) || (du[1] == 0.0f) || (du[2] == 0.0f);
        if (hzA) tri_interval(pv, dv, t0v, t1v);
        if (hzB) tri_interval(pu, du, t0u, t1u);

        const bool overlap = fmaxf(t0v, t0u) <= fminf(t1v, t1u);
        Sres[r][c] = (!ssv && !ssu && overlap) ? 1.0f : 0.0f;
    }
    __syncthreads();

    // ---- write out tile (+ mirror), coalesced float4 ----
    {
        const int row = t >> 3;          // 0..31
        const int c4 = (t & 7) * 4;      // 0,4,...,28
        float4 v;
        v.x = Sres[row][c4 + 0]; v.y = Sres[row][c4 + 1];
        v.z = Sres[row][c4 + 2]; v.w = Sres[row][c4 + 3];
        *(float4*)&out[(size_t)(R + row) * n + C + c4] = v;
        if (tr != tc) {
            float4 w;
            w.x = Sres[c4 + 0][row]; w.y = Sres[c4 + 1][row];
            w.z = Sres[c4 + 2][row]; w.w = Sres[c4 + 3][row];
            *(float4*)&out[(size_t)(C + row) * n + R + c4] = w;
        }
    }
}

extern "C" void kernel_launch(void* const* d_in, const int* in_sizes, int n_in,
                              void* d_out, int out_size, void* d_ws, size_t ws_size,
                              hipStream_t stream) {
    const float* tri = (const float*)d_in[0];
    float* out = (float*)d_out;
    const int n = in_sizes[0] / 9;  // 2048

    const int nt = n / TS;                   // 64
    const int nblocks = nt * (nt + 1) / 2;   // 2080 triu tiles
    dim3 block(TS, 8);
    tile_kernel<<<nblocks, block, 0, stream>>>(tri, out, n);
}

// Round 10
// 70.693 us; speedup vs baseline: 1.0100x; 1.0100x over previous
//
#include <hip/hip_runtime.h>
#include <math.h>

// Triangle-triangle intersection, bit-exact vs the numpy/JAX reference.
//  - Final decisions come from the reference pipeline: ref op order, EPS snap
//    at 1e-6, fp contract OFF, IEEE divides.
//  - Structure: triu 32x32 tiles + survivor compaction (best measured).
//  - R10 = R7's EXACT raw-min/max gate (no margin machinery, no reduction,
//    queue => ~ssv & ~ssu exactly, so phase 2 needs no ss recheck) combined
//    with R9's 2-divide interval fast path (bitwise-identical t values;
//    snapped-zero lanes fall back to the 3-edge reference path).

static constexpr float EPS_SNAP = 1e-6f;
static constexpr int TS = 32;  // tile size; n=2048 divisible

__device__ __forceinline__ float snapz(float x) {
    return (fabsf(x) < EPS_SNAP) ? 0.0f : x;
}

// Reference 3-edge interval (rare path: some snapped distance is exactly 0).
__device__ __forceinline__ void tri_interval(const float p[3], const float d[3],
                                             float& tmin, float& tmax) {
#pragma clang fp contract(off)
    tmin = INFINITY;
    tmax = -INFINITY;
#pragma unroll
    for (int e = 0; e < 3; ++e) {
        const int i0 = e;
        const int i1 = (e + 1) % 3;  // edges (0,1),(1,2),(2,0)
        const float di = d[i0], dj = d[i1];
        const float pi = p[i0], pj = p[i1];
        const bool valid = (di * dj <= 0.0f) && !((di == 0.0f) && (dj == 0.0f));
        const float denom = di - dj;
        const float dsafe = (denom == 0.0f) ? 1.0f : denom;
        const float t = pi + ((pj - pi) * di) / dsafe;
        if (valid) {
            tmin = fminf(tmin, t);
            tmax = fmaxf(tmax, t);
        }
    }
}

// Fast 2-edge interval: valid when all d are snapped-nonzero (mixed signs are
// guaranteed by the exact gate). The two valid edges are those incident to
// the odd-signed vertex o; both use the reference's (i,j) orientation and
// formula -> bitwise identical t values.
__device__ __forceinline__ void tri_interval2(const float p[3], const float d[3],
                                              float& tmin, float& tmax) {
#pragma clang fp contract(off)
    const bool s0 = d[0] > 0.0f, s1 = d[1] > 0.0f;
    const bool s2 = d[2] > 0.0f;
    const int o = (s0 == s1) ? 2 : ((s1 == s2) ? 0 : 1);
    const float po = (o == 0) ? p[0] : ((o == 1) ? p[1] : p[2]);
    const float dO = (o == 0) ? d[0] : ((o == 1) ? d[1] : d[2]);
    const float pj = (o == 0) ? p[1] : ((o == 1) ? p[2] : p[0]);  // (o+1)%3
    const float dj = (o == 0) ? d[1] : ((o == 1) ? d[2] : d[0]);
    const float pi = (o == 0) ? p[2] : ((o == 1) ? p[0] : p[1]);  // (o+2)%3
    const float di = (o == 0) ? d[2] : ((o == 1) ? d[0] : d[1]);
    const float tA = po + ((pj - po) * dO) / (dO - dj);  // ref edge (o, o+1)
    const float tB = pi + ((po - pi) * di) / (di - dO);  // ref edge (o+2, o)
    tmin = fminf(tA, tB);
    tmax = fmaxf(tA, tB);
}

__global__ __launch_bounds__(256, 6) void tile_kernel(
    const float* __restrict__ tri, float* __restrict__ out, int n)
{
#pragma clang fp contract(off)
    const int nt = n / TS;  // 64
    int k = blockIdx.x, tr = 0;
    while (k >= nt - tr) { k -= nt - tr; ++tr; }
    const int tc = tr + k;
    const int R = tr * TS, C = tc * TS;

    __shared__ float Asf[TS * 12];            // row tris, padded to 12 floats
    __shared__ float Bsf[TS * 12];            // col tris
    __shared__ float4 Apl[TS], Bpl[TS];       // planes (normal, offset)
    __shared__ float Sres[TS][TS + 1];        // result tile
    __shared__ unsigned short qbuf[TS * TS];  // survivor queue (r<<5|c)
    __shared__ int s_cnt;

    const int tx = threadIdx.x;  // 0..31 column in tile
    const int ty = threadIdx.y;  // 0..7
    const int t = ty * TS + tx;  // 0..255
    const int lane = t & 63;

    // ---- stage verts (coalesced dwords -> padded LDS rows) ----
    if (t == 0) s_cnt = 0;
    for (int g = t; g < TS * 9; g += 256) {
        const int a = g / 9, c9 = g - a * 9;
        Asf[a * 12 + c9] = tri[(size_t)R * 9 + g];
        Bsf[a * 12 + c9] = tri[(size_t)C * 9 + g];
    }
    // ---- planes from global, concurrent with staging (threads 0..63) ----
    if (t < 2 * TS) {
        const int idx = (t < TS) ? (R + t) : (C + (t - TS));
        const float* V = tri + (size_t)idx * 9;
        float Vv[9];
#pragma unroll
        for (int q = 0; q < 9; ++q) Vv[q] = V[q];
        const float e1x = Vv[3] - Vv[0], e1y = Vv[4] - Vv[1], e1z = Vv[5] - Vv[2];
        const float e2x = Vv[6] - Vv[0], e2y = Vv[7] - Vv[1], e2z = Vv[8] - Vv[2];
        const float nx = e1y * e2z - e1z * e2y;
        const float ny = e1z * e2x - e1x * e2z;
        const float nz = e1x * e2y - e1y * e2x;
        const float d = -(((nx * Vv[0]) + (ny * Vv[1])) + (nz * Vv[2]));
        if (t < TS) Apl[t] = make_float4(nx, ny, nz, d);
        else        Bpl[t - TS] = make_float4(nx, ny, nz, d);
    }
    __syncthreads();

    // ---- phase 1: EXACT raw-distance straddle gate, compact survivors ----
    // all(snap(d)>0) <=> min(raw) >= EPS ; all(snap(d)<0) <=> max(raw) <= -EPS
    // (raw distances in ref order => gate decisions == reference's ssv/ssu)
    float Bv[9];
    {
        const float4 b0 = *(const float4*)&Bsf[tx * 12];
        const float4 b1 = *(const float4*)&Bsf[tx * 12 + 4];
        Bv[0] = b0.x; Bv[1] = b0.y; Bv[2] = b0.z; Bv[3] = b0.w;
        Bv[4] = b1.x; Bv[5] = b1.y; Bv[6] = b1.z; Bv[7] = b1.w;
        Bv[8] = Bsf[tx * 12 + 8];
    }
    const float4 pb = Bpl[tx];

    for (int kk = 0; kk < 4; ++kk) {
        const int r = ty + 8 * kk;
        const float4 a0 = *(const float4*)&Asf[r * 12];
        const float4 a1 = *(const float4*)&Asf[r * 12 + 4];
        const float a8 = Asf[r * 12 + 8];
        const float4 pa = Apl[r];
        // raw signed distances (left-to-right dot + offset, ref order)
        const float dv0 = (((a0.x * pb.x) + (a0.y * pb.y)) + (a0.z * pb.z)) + pb.w;
        const float dv1 = (((a0.w * pb.x) + (a1.x * pb.y)) + (a1.y * pb.z)) + pb.w;
        const float dv2 = (((a1.z * pb.x) + (a1.w * pb.y)) + (a8 * pb.z)) + pb.w;
        const float du0 = (((Bv[0] * pa.x) + (Bv[1] * pa.y)) + (Bv[2] * pa.z)) + pa.w;
        const float du1 = (((Bv[3] * pa.x) + (Bv[4] * pa.y)) + (Bv[5] * pa.z)) + pa.w;
        const float du2 = (((Bv[6] * pa.x) + (Bv[7] * pa.y)) + (Bv[8] * pa.z)) + pa.w;
        const float mnv = fminf(fminf(dv0, dv1), dv2), mxv = fmaxf(fmaxf(dv0, dv1), dv2);
        const float mnu = fminf(fminf(du0, du1), du2), mxu = fmaxf(fmaxf(du0, du1), du2);
        const bool ssv = (mnv >= EPS_SNAP) || (mxv <= -EPS_SNAP);
        const bool ssu = (mnu >= EPS_SNAP) || (mxu <= -EPS_SNAP);
        const int i = R + r, j = C + tx;
        const bool surv = !ssv && !ssu && (i != j);
        Sres[r][tx] = (i == j) ? 1.0f : 0.0f;  // survivors overwritten in phase 2
        const unsigned long long m = __ballot(surv);
        int wb = 0;
        if (lane == 0) {
            const int wcnt = __popcll(m);
            if (wcnt) wb = atomicAdd(&s_cnt, wcnt);
        }
        wb = __shfl(wb, 0);
        if (surv) {
            const int pos = wb + __popcll(m & ((1ull << lane) - 1ull));
            qbuf[pos] = (unsigned short)((r << 5) | tx);
        }
    }
    __syncthreads();

    // ---- phase 2: interval test on survivors (queued => ~ssv & ~ssu) ----
    const int total = s_cnt;
    for (int q = t; q < total; q += 256) {
        const int e = qbuf[q];
        const int r = e >> 5, c = e & 31;

        const float4 pa = Apl[r];
        const float4 pq = Bpl[c];
        const float nax = pa.x, nay = pa.y, naz = pa.z, da = pa.w;
        const float nbx = pq.x, nby = pq.y, nbz = pq.z, db = pq.w;

        // exact snapped distances (reference order)
        float dv[3], du[3];
        {
            const float4 a0 = *(const float4*)&Asf[r * 12];
            const float4 a1 = *(const float4*)&Asf[r * 12 + 4];
            const float a8 = Asf[r * 12 + 8];
            dv[0] = snapz((((a0.x * nbx) + (a0.y * nby)) + (a0.z * nbz)) + db);
            dv[1] = snapz((((a0.w * nbx) + (a1.x * nby)) + (a1.y * nbz)) + db);
            dv[2] = snapz((((a1.z * nbx) + (a1.w * nby)) + (a8 * nbz)) + db);
            const float4 b0 = *(const float4*)&Bsf[c * 12];
            const float4 b1 = *(const float4*)&Bsf[c * 12 + 4];
            const float b8 = Bsf[c * 12 + 8];
            du[0] = snapz((((b0.x * nax) + (b0.y * nay)) + (b0.z * naz)) + da);
            du[1] = snapz((((b0.w * nax) + (b1.x * nay)) + (b1.y * naz)) + da);
            du[2] = snapz((((b1.z * nax) + (b1.w * nay)) + (b8 * naz)) + da);
        }

        // plane-plane line direction, dominant axis (first-occurrence argmax)
        const float Dx = nay * nbz - naz * nby;
        const float Dy = naz * nbx - nax * nbz;
        const float Dz = nax * nby - nay * nbx;
        const float m0 = fabsf(Dx), m1 = fabsf(Dy), m2 = fabsf(Dz);
        int axm = 0;
        float mm = m0;
        if (m1 > mm) { axm = 1; mm = m1; }
        if (m2 > mm) { axm = 2; }

        // projections: indexed LDS reads (bitwise-identical to the selects)
        float pv[3], pu[3];
#pragma unroll
        for (int v = 0; v < 3; ++v) {
            pv[v] = Asf[r * 12 + 3 * v + axm];
            pu[v] = Bsf[c * 12 + 3 * v + axm];
        }

        // 2-divide fast path; rare snapped-zero lanes redo the exact 3-edge ref
        float t0v, t1v, t0u, t1u;
        tri_interval2(pv, dv, t0v, t1v);
        tri_interval2(pu, du, t0u, t1u);
        const bool hzA = (dv[0] == 0.0f) || (dv[1] == 0.0f) || (dv[2] == 0.0f);
        const bool hzB = (du[0] == 0.0f) || (du[1] == 0.0f) || (du[2] == 0.0f);
        if (hzA) tri_interval(pv, dv, t0v, t1v);
        if (hzB) tri_interval(pu, du, t0u, t1u);

        const bool overlap = fmaxf(t0v, t0u) <= fminf(t1v, t1u);
        Sres[r][c] = overlap ? 1.0f : 0.0f;
    }
    __syncthreads();

    // ---- write out tile (+ mirror), coalesced float4 ----
    {
        const int row = t >> 3;          // 0..31
        const int c4 = (t & 7) * 4;      // 0,4,...,28
        float4 v;
        v.x = Sres[row][c4 + 0]; v.y = Sres[row][c4 + 1];
        v.z = Sres[row][c4 + 2]; v.w = Sres[row][c4 + 3];
        *(float4*)&out[(size_t)(R + row) * n + C + c4] = v;
        if (tr != tc) {
            float4 w;
            w.x = Sres[c4 + 0][row]; w.y = Sres[c4 + 1][row];
            w.z = Sres[c4 + 2][row]; w.w = Sres[c4 + 3][row];
            *(float4*)&out[(size_t)(C + row) * n + R + c4] = w;
        }
    }
}

extern "C" void kernel_launch(void* const* d_in, const int* in_sizes, int n_in,
                              void* d_out, int out_size, void* d_ws, size_t ws_size,
                              hipStream_t stream) {
    const float* tri = (const float*)d_in[0];
    float* out = (float*)d_out;
    const int n = in_sizes[0] / 9;  // 2048

    const int nt = n / TS;                   // 64
    const int nblocks = nt * (nt + 1) / 2;   // 2080 triu tiles
    dim3 block(TS, 8);
    tile_kernel<<<nblocks, block, 0, stream>>>(tri, out, n);
}